// Round 10
// baseline (237.154 us; speedup 1.0000x reference)
//
#include <hip/hip_runtime.h>
#include <hip/hip_bf16.h>

// B=2, H=16, S=2048, D=64, DMODEL=1024
// Round 10: attn LDS stride 72 -> 68 (bank step 2 -> every pattern 2-way =
// free; r9 measured 4.3M conflict-cycles ~ 7us from 4-way b64 V reads) with
// zero instruction changes; Q scale-convert fused into attn prologue (reads
// fp32 Q directly; convert_all sheds 2048 blocks / ~24MB). proj = r8 shape.

typedef float  f32x16 __attribute__((ext_vector_type(16)));
typedef float  f32x4v __attribute__((ext_vector_type(4)));
typedef float  f32x2v __attribute__((ext_vector_type(2)));
typedef __bf16 bf16x8 __attribute__((ext_vector_type(8)));
typedef __bf16 bf16x4 __attribute__((ext_vector_type(4)));
typedef __bf16 bf16x2 __attribute__((ext_vector_type(2)));

static constexpr int Bn = 2, Hn = 16, Sn = 2048, Dn = 64, DM = 1024;
static constexpr size_t QKV_ELEMS = (size_t)Bn * Hn * Sn * Dn;   // 4,194,304

#define QSCALE 0.18033688011112042f   // 0.125 * log2(e)

#if __has_builtin(__builtin_amdgcn_cvt_pk_bf16_f32)
static __device__ __forceinline__ unsigned pack2(float a, float b) {
  bf16x2 t = __builtin_amdgcn_cvt_pk_bf16_f32(a, b);
  union { bf16x2 v; unsigned u; } c; c.v = t; return c.u;
}
#else
static __device__ __forceinline__ unsigned pack2(float a, float b) {
  union { __bf16 h; unsigned short s; } ua, ub;
  ua.h = (__bf16)a; ub.h = (__bf16)b;
  return (unsigned)ua.s | ((unsigned)ub.s << 16);
}
#endif

static __device__ __forceinline__ void unzip8(const unsigned* wds, bf16x8* r0, bf16x8* r1) {
  union { unsigned u[4]; bf16x8 v; } a, b;
#pragma unroll
  for (int i = 0; i < 4; ++i) {
    unsigned lo = wds[2 * i], hi = wds[2 * i + 1];
    a.u[i] = (lo & 0xffffu) | (hi << 16);
    b.u[i] = (lo >> 16) | (hi & 0xffff0000u);
  }
  *r0 = a.v; *r1 = b.v;
}

// ------------------------------------------------- fused converts (1 kernel)
// [0,2048) K cvt; [2048,3072) V-T; [3072,3328) W-T. (Q handled inside attn.)
__global__ __launch_bounds__(256) void convert_all(
    const float* __restrict__ k,
    const float* __restrict__ v, const float* __restrict__ w,
    __bf16* __restrict__ ko,
    __bf16* __restrict__ vt, __bf16* __restrict__ wt) {
  __shared__ __bf16 T[64][74];
  const int bid = blockIdx.x, t = threadIdx.x;

  if (bid < 2048) {
    size_t i = ((size_t)bid * 256 + t) * 8;
    f32x4v a = *(const f32x4v*)(k + i);
    f32x4v b = *(const f32x4v*)(k + i + 4);
    bf16x8 o;
#pragma unroll
    for (int j = 0; j < 4; ++j) { o[j] = (__bf16)a[j]; o[4 + j] = (__bf16)b[j]; }
    *(bf16x8*)(ko + i) = o;
    return;
  }

  const float* s0;
  __bf16* dst0;
  size_t dst_stride;
  {
    const int r = t >> 2, c0 = (t & 3) * 16;
    if (bid < 3072) {
      const int idx = bid - 2048;
      const int kv0 = (idx & 31) * 64, bh = idx >> 5;
      s0 = v + ((size_t)bh * Sn + kv0 + r) * Dn + c0;
      dst0 = vt + (size_t)bh * Dn * Sn + kv0;
      dst_stride = Sn;
    } else {
      const int idx = bid - 3072;
      const int nt = (idx & 15) * 64, kt = (idx >> 4) * 64;
      s0 = w + (size_t)(kt + r) * DM + nt + c0;
      dst0 = wt + (size_t)nt * DM + kt;
      dst_stride = DM;
    }
    union { bf16x8 v8; unsigned u[4]; } o0, o1;
#pragma unroll
    for (int i = 0; i < 2; ++i) {
      f32x4v f = *(const f32x4v*)(s0 + i * 4);
#pragma unroll
      for (int j = 0; j < 4; ++j) o0.v8[i * 4 + j] = (__bf16)f[j];
    }
#pragma unroll
    for (int i = 0; i < 2; ++i) {
      f32x4v f = *(const f32x4v*)(s0 + 8 + i * 4);
#pragma unroll
      for (int j = 0; j < 4; ++j) o1.v8[i * 4 + j] = (__bf16)f[j];
    }
#pragma unroll
    for (int j = 0; j < 4; ++j) {
      *(unsigned*)&T[r][c0 + 2 * j]     = o0.u[j];
      *(unsigned*)&T[r][c0 + 8 + 2 * j] = o1.u[j];
    }
  }
  __syncthreads();
  const int rp = t >> 3, k0 = (t & 7) * 8;
  unsigned wds[8];
#pragma unroll
  for (int i = 0; i < 8; ++i) wds[i] = *(const unsigned*)&T[k0 + i][2 * rp];
  bf16x8 r0, r1; unzip8(wds, &r0, &r1);
  __bf16* d0 = dst0 + (size_t)(2 * rp) * dst_stride + k0;
  *(bf16x8*)d0 = r0;
  *(bf16x8*)(d0 + dst_stride) = r1;
}

// ---------------------------------------------------------------- attention
// grid (S/64, H, B) = 1024 blocks = 4 blocks/CU, 4 waves =
// (qg x 32q, kh x 32kv-half). LDS stride 68: bank step 2 -> all patterns
// 2-way (free). Q read as fp32 + converted in prologue.
__global__ __launch_bounds__(256, 4) void attn(
    const float* __restrict__ Qf, const __bf16* __restrict__ Kb,
    const __bf16* __restrict__ Vtg, __bf16* __restrict__ Cc) {
  const int tid = threadIdx.x;
  const int wave = tid >> 6, lane = tid & 63;
  const int ln = lane & 31, g = lane >> 5;
  const int qg = wave >> 1, kh = wave & 1;
  const int qb = blockIdx.x, h = blockIdx.y, bz = blockIdx.z;

  __shared__ __bf16 smem[2][2][64][68];      // 34816 B -> 4 blocks/CU
  __bf16 (*Ks)[64][68] = smem[0];            // [buf][kv][d]
  __bf16 (*Vs)[64][68] = smem[1];            // [buf][d][kv]

  const size_t hoff = (size_t)(bz * Hn + h) * Sn * Dn;
  const float*  Qp = Qf + hoff + (size_t)(qb * 64 + qg * 32) * Dn;
  const __bf16* Kp = Kb + hoff;      // [kv][d]
  const __bf16* Vp = Vtg + hoff;     // [d][kv]

  // Q A-fragments: fp32 load + scale + cvt (prologue only)
  bf16x8 qf[4];
#pragma unroll
  for (int ks = 0; ks < 4; ++ks) {
    const float* qp = Qp + (size_t)ln * Dn + ks * 16 + g * 8;
    f32x4v f0 = *(const f32x4v*)qp;
    f32x4v f1 = *(const f32x4v*)(qp + 4);
#pragma unroll
    for (int j = 0; j < 4; ++j) {
      qf[ks][j]     = (__bf16)(f0[j] * QSCALE);
      qf[ks][4 + j] = (__bf16)(f1[j] * QSCALE);
    }
  }

  const int sr = tid >> 2, sc = (tid & 3) * 16;
  const __bf16* kbase = Kp + (size_t)sr * Dn + sc;
  const __bf16* vbase = Vp + (size_t)sr * Sn + sc;

  bf16x8 k0r = *(const bf16x8*)kbase, k1r = *(const bf16x8*)(kbase + 8);
  bf16x8 v0r = *(const bf16x8*)vbase, v1r = *(const bf16x8*)(vbase + 8);
  *(bf16x8*)&Ks[0][sr][sc]     = k0r;
  *(bf16x8*)&Ks[0][sr][sc + 8] = k1r;
  *(bf16x8*)&Vs[0][sr][sc]     = v0r;
  *(bf16x8*)&Vs[0][sr][sc + 8] = v1r;
  k0r = *(const bf16x8*)(kbase + (size_t)64 * Dn);
  k1r = *(const bf16x8*)(kbase + (size_t)64 * Dn + 8);
  v0r = *(const bf16x8*)(vbase + 64);
  v1r = *(const bf16x8*)(vbase + 64 + 8);
  __syncthreads();

  f32x16 O0 = {}, O1 = {};                   // O^T halves: d in [0,32),[32,64)
  float Lown = 0.0f;
  constexpr int NT = Sn / 64;

  for (int kt = 0; kt < NT; ++kt) {
    const int buf = kt & 1;

    bf16x8 kf[4];
#pragma unroll
    for (int ks = 0; ks < 4; ++ks)
      kf[ks] = *(const bf16x8*)&Ks[buf][kh * 32 + ln][ks * 16 + g * 8];

    f32x16 s = {};
#pragma unroll
    for (int ks = 0; ks < 4; ++ks)
      s = __builtin_amdgcn_mfma_f32_32x32x16_bf16(kf[ks], qf[ks], s, 0, 0, 0);
    float p[16];
#pragma unroll
    for (int r = 0; r < 16; ++r) p[r] = __builtin_amdgcn_exp2f(s[r]);
    f32x2v s2 = {0.0f, 0.0f};
#pragma unroll
    for (int tt = 0; tt < 8; ++tt) { f32x2v t2 = {p[2 * tt], p[2 * tt + 1]}; s2 += t2; }
    Lown += s2[0] + s2[1];
    unsigned w[8];
#pragma unroll
    for (int tt = 0; tt < 8; ++tt) w[tt] = pack2(p[2 * tt], p[2 * tt + 1]);

    if (kt + 1 < NT) {
      const int nb = buf ^ 1;
      *(bf16x8*)&Ks[nb][sr][sc]     = k0r;
      *(bf16x8*)&Ks[nb][sr][sc + 8] = k1r;
      *(bf16x8*)&Vs[nb][sr][sc]     = v0r;
      *(bf16x8*)&Vs[nb][sr][sc + 8] = v1r;
      if (kt + 2 < NT) {
        const __bf16* kp = kbase + (size_t)(kt + 2) * 64 * Dn;
        k0r = *(const bf16x8*)kp; k1r = *(const bf16x8*)(kp + 8);
        const __bf16* vp = vbase + (kt + 2) * 64;
        v0r = *(const bf16x8*)vp; v1r = *(const bf16x8*)(vp + 8);
      }
    }

    // PV with permuted kv order: step s4 covers C/D regs [8*s4, 8*s4+8);
    // B-frag k=g*8+j <-> kv_local = kh*32 + s4*16 + g*4 + 8*(j>>2) + (j&3),
    // so B words are w[s4*4..+3] verbatim; V^T supplies k as b64 pairs.
#pragma unroll
    for (int s4 = 0; s4 < 2; ++s4) {
      const int cb = kh * 32 + s4 * 16 + g * 4;
      union { bf16x4 h[2]; bf16x8 v; } vf0, vf1;
      vf0.h[0] = *(const bf16x4*)&Vs[buf][ln][cb];
      vf0.h[1] = *(const bf16x4*)&Vs[buf][ln][cb + 8];
      vf1.h[0] = *(const bf16x4*)&Vs[buf][32 + ln][cb];
      vf1.h[1] = *(const bf16x4*)&Vs[buf][32 + ln][cb + 8];
      union { unsigned u[4]; bf16x8 v; } pu;
      pu.u[0] = w[s4 * 4 + 0];
      pu.u[1] = w[s4 * 4 + 1];
      pu.u[2] = w[s4 * 4 + 2];
      pu.u[3] = w[s4 * 4 + 3];
      O0 = __builtin_amdgcn_mfma_f32_32x32x16_bf16(vf0.v, pu.v, O0, 0, 0, 0);
      O1 = __builtin_amdgcn_mfma_f32_32x32x16_bf16(vf1.v, pu.v, O1, 0, 0, 0);
    }
    __syncthreads();
  }

  // ---- kh pair-reduction via LDS; normalize; transpose; coalesced store ----
  const float Lred = Lown + __shfl_xor(Lown, 32);
  float* Ex = (float*)smem;                  // [2*64][36] f32 = 18432 B
  const int slot = (qg * 64 + lane) * 36;
  if (kh == 1) {
#pragma unroll
    for (int i = 0; i < 4; ++i) {
      f32x4v t = {O0[4 * i], O0[4 * i + 1], O0[4 * i + 2], O0[4 * i + 3]};
      *(f32x4v*)&Ex[slot + 4 * i] = t;
    }
#pragma unroll
    for (int i = 0; i < 4; ++i) {
      f32x4v t = {O1[4 * i], O1[4 * i + 1], O1[4 * i + 2], O1[4 * i + 3]};
      *(f32x4v*)&Ex[slot + 16 + 4 * i] = t;
    }
    Ex[slot + 32] = Lred;
  }
  __syncthreads();
  float inv = 0.0f;
  if (kh == 0) {
#pragma unroll
    for (int i = 0; i < 4; ++i) {
      f32x4v t = *(const f32x4v*)&Ex[slot + 4 * i];
#pragma unroll
      for (int c = 0; c < 4; ++c) O0[4 * i + c] += t[c];
    }
#pragma unroll
    for (int i = 0; i < 4; ++i) {
      f32x4v t = *(const f32x4v*)&Ex[slot + 16 + 4 * i];
#pragma unroll
      for (int c = 0; c < 4; ++c) O1[4 * i + c] += t[c];
    }
    inv = 1.0f / (Lred + Ex[slot + 32]);
  }
  __syncthreads();
  __bf16* T = (__bf16*)smem;                 // [64][72] bf16 = 9216 B
  if (kh == 0) {
#pragma unroll
    for (int dh = 0; dh < 2; ++dh) {
#pragma unroll
      for (int a = 0; a < 4; ++a) {
        const f32x16 O = dh ? O1 : O0;
        bf16x4 t4;
#pragma unroll
        for (int c = 0; c < 4; ++c) t4[c] = (__bf16)(O[4 * a + c] * inv);
        *(bf16x4*)&T[(qg * 32 + ln) * 72 + dh * 32 + 8 * a + 4 * g] = t4;
      }
    }
  }
  __syncthreads();
  const int q0 = qb * 64;
#pragma unroll
  for (int i = 0; i < 2; ++i) {
    const int rq = i * 32 + (tid >> 3);
    const int c8 = (tid & 7) * 8;
    bf16x8 o = *(const bf16x8*)&T[rq * 72 + c8];
    size_t base = (((size_t)bz * Sn + q0 + rq) * Hn + h) * Dn + c8;
    *(bf16x8*)&Cc[base] = o;
  }
}

// ---------------------------------------------------------------- projection
// out(4096,1024) = concat @ W + b. 128x64 tile, 512 threads = 8 waves
// (wave = M-quadrant mq x N-half nh), dbuf, one barrier/iter. 16 waves/CU.
__global__ __launch_bounds__(512, 2) void proj(
    const __bf16* __restrict__ A, const __bf16* __restrict__ Wt,
    const float* __restrict__ bias, float* __restrict__ out) {
  const int tid = threadIdx.x, wave = tid >> 6, lane = tid & 63;
  const int ln = lane & 31, g = lane >> 5;
  const int mq = wave >> 1, nh = wave & 1;
  const int bm = blockIdx.x, bn = blockIdx.y;
  __shared__ __bf16 As[2][128][72];
  __shared__ __bf16 Bs[2][64][72];
  const int ar = tid >> 2, ac = (tid & 3) * 16;   // A: 2 b128/thread
  const int rb = tid >> 3, cb = (tid & 7) * 8;    // B: 1 b128/thread
  f32x16 acc = {};
  const __bf16* Ap = A + (size_t)(bm * 128) * DM;
  const __bf16* Wp = Wt + (size_t)(bn * 64) * DM;

  bf16x8 a0, a1, b0;
  {
    const __bf16* ap = Ap + (size_t)ar * DM + ac;
    a0 = *(const bf16x8*)ap; a1 = *(const bf16x8*)(ap + 8);
    b0 = *(const bf16x8*)(Wp + (size_t)rb * DM + cb);
  }
  *(bf16x8*)&As[0][ar][ac]     = a0;
  *(bf16x8*)&As[0][ar][ac + 8] = a1;
  *(bf16x8*)&Bs[0][rb][cb]     = b0;
  {
    const __bf16* ap = Ap + (size_t)ar * DM + 64 + ac;
    a0 = *(const bf16x8*)ap; a1 = *(const bf16x8*)(ap + 8);
    b0 = *(const bf16x8*)(Wp + (size_t)rb * DM + 64 + cb);
  }
  __syncthreads();

  constexpr int KT = DM / 64;
  for (int kt = 0; kt < KT; ++kt) {
    const int buf = kt & 1;
#pragma unroll
    for (int ks = 0; ks < 4; ++ks) {
      bf16x8 af = *(const bf16x8*)&As[buf][mq * 32 + ln][ks * 16 + g * 8];
      bf16x8 wf = *(const bf16x8*)&Bs[buf][nh * 32 + ln][ks * 16 + g * 8];
      acc = __builtin_amdgcn_mfma_f32_32x32x16_bf16(af, wf, acc, 0, 0, 0);
    }
    if (kt + 1 < KT) {
      const int nb = buf ^ 1;
      *(bf16x8*)&As[nb][ar][ac]     = a0;
      *(bf16x8*)&As[nb][ar][ac + 8] = a1;
      *(bf16x8*)&Bs[nb][rb][cb]     = b0;
      if (kt + 2 < KT) {
        const __bf16* ap = Ap + (size_t)ar * DM + (kt + 2) * 64 + ac;
        a0 = *(const bf16x8*)ap; a1 = *(const bf16x8*)(ap + 8);
        b0 = *(const bf16x8*)(Wp + (size_t)rb * DM + (kt + 2) * 64 + cb);
      }
    }
    __syncthreads();
  }
  const float bv = bias[bn * 64 + nh * 32 + ln];
#pragma unroll
  for (int r = 0; r < 16; ++r) {
    int row = bm * 128 + mq * 32 + (r & 3) + 8 * (r >> 2) + 4 * g;
    out[(size_t)row * DM + bn * 64 + nh * 32 + ln] = acc[r] + bv;
  }
}

// ---------------------------------------------------------------- launch
extern "C" void kernel_launch(void* const* d_in, const int* in_sizes, int n_in,
                              void* d_out, int out_size, void* d_ws, size_t ws_size,
                              hipStream_t stream) {
  const float* Q = (const float*)d_in[0];
  const float* K = (const float*)d_in[1];
  const float* V = (const float*)d_in[2];
  const float* W = (const float*)d_in[3];
  const float* b = (const float*)d_in[4];
  float* out = (float*)d_out;

  __bf16* ws  = (__bf16*)d_ws;
  __bf16* Kb  = ws;
  __bf16* Vtg = Kb + QKV_ELEMS;               // (b,h,d,kv) bf16
  __bf16* Cc  = Vtg + QKV_ELEMS;              // concat (B,S,H,D) bf16
  __bf16* Wt  = Cc + QKV_ELEMS;               // (n,k) bf16

  convert_all<<<dim3(3328, 1, 1), 256, 0, stream>>>(K, V, W, Kb, Vtg, Wt);
  attn<<<dim3(Sn / 64, Hn, Bn), 256, 0, stream>>>(Q, Kb, Vtg, Cc);
  proj<<<dim3(Bn * Sn / 128, DM / 64, 1), 512, 0, stream>>>(Cc, Wt, b, out);
}

// Round 11
// 156.733 us; speedup vs baseline: 1.5131x; 1.5131x over previous
//
#include <hip/hip_runtime.h>
#include <hip/hip_bf16.h>

// B=2, H=16, S=2048, D=64, DMODEL=1024
// Round 11: r10 post-mortem -- stride 68 broke 16B alignment of b128 LDS ops
// (136B row stride => odd rows at addr%16==8 => split/microcoded DS, 3x wall).
// Revert to stride 72 (r9's measured-54us geometry). Keep r10's Q-fusion
// (rest improved ~15us). New: V columns stored PERMUTED in staging (register
// re-association only) so PV fragments read as 4 aligned b128 instead of
// 8 4-way-conflicting b64 (r9's 4.3M conflict cycles).

typedef float  f32x16 __attribute__((ext_vector_type(16)));
typedef float  f32x4v __attribute__((ext_vector_type(4)));
typedef float  f32x2v __attribute__((ext_vector_type(2)));
typedef __bf16 bf16x8 __attribute__((ext_vector_type(8)));
typedef __bf16 bf16x4 __attribute__((ext_vector_type(4)));
typedef __bf16 bf16x2 __attribute__((ext_vector_type(2)));

static constexpr int Bn = 2, Hn = 16, Sn = 2048, Dn = 64, DM = 1024;
static constexpr size_t QKV_ELEMS = (size_t)Bn * Hn * Sn * Dn;   // 4,194,304

#define QSCALE 0.18033688011112042f   // 0.125 * log2(e)

#if __has_builtin(__builtin_amdgcn_cvt_pk_bf16_f32)
static __device__ __forceinline__ unsigned pack2(float a, float b) {
  bf16x2 t = __builtin_amdgcn_cvt_pk_bf16_f32(a, b);
  union { bf16x2 v; unsigned u; } c; c.v = t; return c.u;
}
#else
static __device__ __forceinline__ unsigned pack2(float a, float b) {
  union { __bf16 h; unsigned short s; } ua, ub;
  ua.h = (__bf16)a; ub.h = (__bf16)b;
  return (unsigned)ua.s | ((unsigned)ub.s << 16);
}
#endif

static __device__ __forceinline__ void unzip8(const unsigned* wds, bf16x8* r0, bf16x8* r1) {
  union { unsigned u[4]; bf16x8 v; } a, b;
#pragma unroll
  for (int i = 0; i < 4; ++i) {
    unsigned lo = wds[2 * i], hi = wds[2 * i + 1];
    a.u[i] = (lo & 0xffffu) | (hi << 16);
    b.u[i] = (lo >> 16) | (hi & 0xffff0000u);
  }
  *r0 = a.v; *r1 = b.v;
}

// ------------------------------------------------- fused converts (1 kernel)
// [0,2048) K cvt; [2048,3072) V-T; [3072,3328) W-T. (Q handled inside attn.)
__global__ __launch_bounds__(256) void convert_all(
    const float* __restrict__ k,
    const float* __restrict__ v, const float* __restrict__ w,
    __bf16* __restrict__ ko,
    __bf16* __restrict__ vt, __bf16* __restrict__ wt) {
  __shared__ __bf16 T[64][74];
  const int bid = blockIdx.x, t = threadIdx.x;

  if (bid < 2048) {
    size_t i = ((size_t)bid * 256 + t) * 8;
    f32x4v a = *(const f32x4v*)(k + i);
    f32x4v b = *(const f32x4v*)(k + i + 4);
    bf16x8 o;
#pragma unroll
    for (int j = 0; j < 4; ++j) { o[j] = (__bf16)a[j]; o[4 + j] = (__bf16)b[j]; }
    *(bf16x8*)(ko + i) = o;
    return;
  }

  const float* s0;
  __bf16* dst0;
  size_t dst_stride;
  {
    const int r = t >> 2, c0 = (t & 3) * 16;
    if (bid < 3072) {
      const int idx = bid - 2048;
      const int kv0 = (idx & 31) * 64, bh = idx >> 5;
      s0 = v + ((size_t)bh * Sn + kv0 + r) * Dn + c0;
      dst0 = vt + (size_t)bh * Dn * Sn + kv0;
      dst_stride = Sn;
    } else {
      const int idx = bid - 3072;
      const int nt = (idx & 15) * 64, kt = (idx >> 4) * 64;
      s0 = w + (size_t)(kt + r) * DM + nt + c0;
      dst0 = wt + (size_t)nt * DM + kt;
      dst_stride = DM;
    }
    union { bf16x8 v8; unsigned u[4]; } o0, o1;
#pragma unroll
    for (int i = 0; i < 2; ++i) {
      f32x4v f = *(const f32x4v*)(s0 + i * 4);
#pragma unroll
      for (int j = 0; j < 4; ++j) o0.v8[i * 4 + j] = (__bf16)f[j];
    }
#pragma unroll
    for (int i = 0; i < 2; ++i) {
      f32x4v f = *(const f32x4v*)(s0 + 8 + i * 4);
#pragma unroll
      for (int j = 0; j < 4; ++j) o1.v8[i * 4 + j] = (__bf16)f[j];
    }
#pragma unroll
    for (int j = 0; j < 4; ++j) {
      *(unsigned*)&T[r][c0 + 2 * j]     = o0.u[j];
      *(unsigned*)&T[r][c0 + 8 + 2 * j] = o1.u[j];
    }
  }
  __syncthreads();
  const int rp = t >> 3, k0 = (t & 7) * 8;
  unsigned wds[8];
#pragma unroll
  for (int i = 0; i < 8; ++i) wds[i] = *(const unsigned*)&T[k0 + i][2 * rp];
  bf16x8 r0, r1; unzip8(wds, &r0, &r1);
  __bf16* d0 = dst0 + (size_t)(2 * rp) * dst_stride + k0;
  *(bf16x8*)d0 = r0;
  *(bf16x8*)(d0 + dst_stride) = r1;
}

// ---------------------------------------------------------------- attention
// grid (S/64, H, B) = 1024 blocks = 4 blocks/CU, 4 waves =
// (qg x 32q, kh x 32kv-half). LDS stride 72 (144B, 16B-aligned rows).
// Q read fp32 + converted in prologue. V stored column-permuted per 16-block
// ([0..3,8..11 | 4..7,12..15]) so PV fragments are contiguous b128 reads.
__global__ __launch_bounds__(256, 4) void attn(
    const float* __restrict__ Qf, const __bf16* __restrict__ Kb,
    const __bf16* __restrict__ Vtg, __bf16* __restrict__ Cc) {
  const int tid = threadIdx.x;
  const int wave = tid >> 6, lane = tid & 63;
  const int ln = lane & 31, g = lane >> 5;
  const int qg = wave >> 1, kh = wave & 1;
  const int qb = blockIdx.x, h = blockIdx.y, bz = blockIdx.z;

  __shared__ __bf16 smem[2][2][64][72];      // 36864 B -> 4 blocks/CU
  __bf16 (*Ks)[64][72] = smem[0];            // [buf][kv][d]
  __bf16 (*Vs)[64][72] = smem[1];            // [buf][d][kv-permuted]

  const size_t hoff = (size_t)(bz * Hn + h) * Sn * Dn;
  const float*  Qp = Qf + hoff + (size_t)(qb * 64 + qg * 32) * Dn;
  const __bf16* Kp = Kb + hoff;      // [kv][d]
  const __bf16* Vp = Vtg + hoff;     // [d][kv]

  // Q A-fragments: fp32 load + scale + cvt (prologue only)
  bf16x8 qf[4];
#pragma unroll
  for (int ks = 0; ks < 4; ++ks) {
    const float* qp = Qp + (size_t)ln * Dn + ks * 16 + g * 8;
    f32x4v f0 = *(const f32x4v*)qp;
    f32x4v f1 = *(const f32x4v*)(qp + 4);
#pragma unroll
    for (int j = 0; j < 4; ++j) {
      qf[ks][j]     = (__bf16)(f0[j] * QSCALE);
      qf[ks][4 + j] = (__bf16)(f1[j] * QSCALE);
    }
  }

  const int sr = tid >> 2, sc = (tid & 3) * 16;
  const __bf16* kbase = Kp + (size_t)sr * Dn + sc;
  const __bf16* vbase = Vp + (size_t)sr * Sn + sc;

  // store V 16-block permuted: out0 = [v0.lo, v1.lo], out1 = [v0.hi, v1.hi]
  bf16x8 k0r = *(const bf16x8*)kbase, k1r = *(const bf16x8*)(kbase + 8);
  bf16x8 v0r = *(const bf16x8*)vbase, v1r = *(const bf16x8*)(vbase + 8);
  {
    *(bf16x8*)&Ks[0][sr][sc]     = k0r;
    *(bf16x8*)&Ks[0][sr][sc + 8] = k1r;
    union { bf16x8 v; bf16x4 h[2]; } u0, u1; u0.v = v0r; u1.v = v1r;
    union { bf16x4 h[2]; bf16x8 v; } w0, w1;
    w0.h[0] = u0.h[0]; w0.h[1] = u1.h[0];
    w1.h[0] = u0.h[1]; w1.h[1] = u1.h[1];
    *(bf16x8*)&Vs[0][sr][sc]     = w0.v;
    *(bf16x8*)&Vs[0][sr][sc + 8] = w1.v;
  }
  k0r = *(const bf16x8*)(kbase + (size_t)64 * Dn);
  k1r = *(const bf16x8*)(kbase + (size_t)64 * Dn + 8);
  v0r = *(const bf16x8*)(vbase + 64);
  v1r = *(const bf16x8*)(vbase + 64 + 8);
  __syncthreads();

  f32x16 O0 = {}, O1 = {};                   // O^T halves: d in [0,32),[32,64)
  float Lown = 0.0f;
  constexpr int NT = Sn / 64;

  for (int kt = 0; kt < NT; ++kt) {
    const int buf = kt & 1;

    bf16x8 kf[4];
#pragma unroll
    for (int ks = 0; ks < 4; ++ks)
      kf[ks] = *(const bf16x8*)&Ks[buf][kh * 32 + ln][ks * 16 + g * 8];

    f32x16 s = {};
#pragma unroll
    for (int ks = 0; ks < 4; ++ks)
      s = __builtin_amdgcn_mfma_f32_32x32x16_bf16(kf[ks], qf[ks], s, 0, 0, 0);
    float p[16];
#pragma unroll
    for (int r = 0; r < 16; ++r) p[r] = __builtin_amdgcn_exp2f(s[r]);
    f32x2v s2 = {0.0f, 0.0f};
#pragma unroll
    for (int tt = 0; tt < 8; ++tt) { f32x2v t2 = {p[2 * tt], p[2 * tt + 1]}; s2 += t2; }
    Lown += s2[0] + s2[1];
    unsigned w[8];
#pragma unroll
    for (int tt = 0; tt < 8; ++tt) w[tt] = pack2(p[2 * tt], p[2 * tt + 1]);

    if (kt + 1 < NT) {
      const int nb = buf ^ 1;
      *(bf16x8*)&Ks[nb][sr][sc]     = k0r;
      *(bf16x8*)&Ks[nb][sr][sc + 8] = k1r;
      union { bf16x8 v; bf16x4 h[2]; } u0, u1; u0.v = v0r; u1.v = v1r;
      union { bf16x4 h[2]; bf16x8 v; } w0, w1;
      w0.h[0] = u0.h[0]; w0.h[1] = u1.h[0];
      w1.h[0] = u0.h[1]; w1.h[1] = u1.h[1];
      *(bf16x8*)&Vs[nb][sr][sc]     = w0.v;
      *(bf16x8*)&Vs[nb][sr][sc + 8] = w1.v;
      if (kt + 2 < NT) {
        const __bf16* kp = kbase + (size_t)(kt + 2) * 64 * Dn;
        k0r = *(const bf16x8*)kp; k1r = *(const bf16x8*)(kp + 8);
        const __bf16* vp = vbase + (kt + 2) * 64;
        v0r = *(const bf16x8*)vp; v1r = *(const bf16x8*)(vp + 8);
      }
    }

    // PV with permuted kv order: step s4 covers C/D regs [8*s4, 8*s4+8);
    // B words are w[s4*4..+3] verbatim; V^T (permuted columns) supplies the
    // matching 8 kv as ONE contiguous b128 at col kh*32 + s4*16 + g*8.
#pragma unroll
    for (int s4 = 0; s4 < 2; ++s4) {
      const int cb = kh * 32 + s4 * 16 + g * 8;
      bf16x8 vf0 = *(const bf16x8*)&Vs[buf][ln][cb];
      bf16x8 vf1 = *(const bf16x8*)&Vs[buf][32 + ln][cb];
      union { unsigned u[4]; bf16x8 v; } pu;
      pu.u[0] = w[s4 * 4 + 0];
      pu.u[1] = w[s4 * 4 + 1];
      pu.u[2] = w[s4 * 4 + 2];
      pu.u[3] = w[s4 * 4 + 3];
      O0 = __builtin_amdgcn_mfma_f32_32x32x16_bf16(vf0, pu.v, O0, 0, 0, 0);
      O1 = __builtin_amdgcn_mfma_f32_32x32x16_bf16(vf1, pu.v, O1, 0, 0, 0);
    }
    __syncthreads();
  }

  // ---- kh pair-reduction via LDS; normalize; transpose; coalesced store ----
  const float Lred = Lown + __shfl_xor(Lown, 32);
  float* Ex = (float*)smem;                  // [2*64][36] f32 = 18432 B
  const int slot = (qg * 64 + lane) * 36;
  if (kh == 1) {
#pragma unroll
    for (int i = 0; i < 4; ++i) {
      f32x4v t = {O0[4 * i], O0[4 * i + 1], O0[4 * i + 2], O0[4 * i + 3]};
      *(f32x4v*)&Ex[slot + 4 * i] = t;
    }
#pragma unroll
    for (int i = 0; i < 4; ++i) {
      f32x4v t = {O1[4 * i], O1[4 * i + 1], O1[4 * i + 2], O1[4 * i + 3]};
      *(f32x4v*)&Ex[slot + 16 + 4 * i] = t;
    }
    Ex[slot + 32] = Lred;
  }
  __syncthreads();
  float inv = 0.0f;
  if (kh == 0) {
#pragma unroll
    for (int i = 0; i < 4; ++i) {
      f32x4v t = *(const f32x4v*)&Ex[slot + 4 * i];
#pragma unroll
      for (int c = 0; c < 4; ++c) O0[4 * i + c] += t[c];
    }
#pragma unroll
    for (int i = 0; i < 4; ++i) {
      f32x4v t = *(const f32x4v*)&Ex[slot + 16 + 4 * i];
#pragma unroll
      for (int c = 0; c < 4; ++c) O1[4 * i + c] += t[c];
    }
    inv = 1.0f / (Lred + Ex[slot + 32]);
  }
  __syncthreads();
  __bf16* T = (__bf16*)smem;                 // [64][72] bf16 = 9216 B
  if (kh == 0) {
#pragma unroll
    for (int dh = 0; dh < 2; ++dh) {
#pragma unroll
      for (int a = 0; a < 4; ++a) {
        const f32x16 O = dh ? O1 : O0;
        bf16x4 t4;
#pragma unroll
        for (int c = 0; c < 4; ++c) t4[c] = (__bf16)(O[4 * a + c] * inv);
        *(bf16x4*)&T[(qg * 32 + ln) * 72 + dh * 32 + 8 * a + 4 * g] = t4;
      }
    }
  }
  __syncthreads();
  const int q0 = qb * 64;
#pragma unroll
  for (int i = 0; i < 2; ++i) {
    const int rq = i * 32 + (tid >> 3);
    const int c8 = (tid & 7) * 8;
    bf16x8 o = *(const bf16x8*)&T[rq * 72 + c8];
    size_t base = (((size_t)bz * Sn + q0 + rq) * Hn + h) * Dn + c8;
    *(bf16x8*)&Cc[base] = o;
  }
}

// ---------------------------------------------------------------- projection
// out(4096,1024) = concat @ W + b. 128x64 tile, 512 threads = 8 waves
// (wave = M-quadrant mq x N-half nh), dbuf, one barrier/iter. 16 waves/CU.
__global__ __launch_bounds__(512, 2) void proj(
    const __bf16* __restrict__ A, const __bf16* __restrict__ Wt,
    const float* __restrict__ bias, float* __restrict__ out) {
  const int tid = threadIdx.x, wave = tid >> 6, lane = tid & 63;
  const int ln = lane & 31, g = lane >> 5;
  const int mq = wave >> 1, nh = wave & 1;
  const int bm = blockIdx.x, bn = blockIdx.y;
  __shared__ __bf16 As[2][128][72];
  __shared__ __bf16 Bs[2][64][72];
  const int ar = tid >> 2, ac = (tid & 3) * 16;   // A: 2 b128/thread
  const int rb = tid >> 3, cb = (tid & 7) * 8;    // B: 1 b128/thread
  f32x16 acc = {};
  const __bf16* Ap = A + (size_t)(bm * 128) * DM;
  const __bf16* Wp = Wt + (size_t)(bn * 64) * DM;

  bf16x8 a0, a1, b0;
  {
    const __bf16* ap = Ap + (size_t)ar * DM + ac;
    a0 = *(const bf16x8*)ap; a1 = *(const bf16x8*)(ap + 8);
    b0 = *(const bf16x8*)(Wp + (size_t)rb * DM + cb);
  }
  *(bf16x8*)&As[0][ar][ac]     = a0;
  *(bf16x8*)&As[0][ar][ac + 8] = a1;
  *(bf16x8*)&Bs[0][rb][cb]     = b0;
  {
    const __bf16* ap = Ap + (size_t)ar * DM + 64 + ac;
    a0 = *(const bf16x8*)ap; a1 = *(const bf16x8*)(ap + 8);
    b0 = *(const bf16x8*)(Wp + (size_t)rb * DM + 64 + cb);
  }
  __syncthreads();

  constexpr int KT = DM / 64;
  for (int kt = 0; kt < KT; ++kt) {
    const int buf = kt & 1;
#pragma unroll
    for (int ks = 0; ks < 4; ++ks) {
      bf16x8 af = *(const bf16x8*)&As[buf][mq * 32 + ln][ks * 16 + g * 8];
      bf16x8 wf = *(const bf16x8*)&Bs[buf][nh * 32 + ln][ks * 16 + g * 8];
      acc = __builtin_amdgcn_mfma_f32_32x32x16_bf16(af, wf, acc, 0, 0, 0);
    }
    if (kt + 1 < KT) {
      const int nb = buf ^ 1;
      *(bf16x8*)&As[nb][ar][ac]     = a0;
      *(bf16x8*)&As[nb][ar][ac + 8] = a1;
      *(bf16x8*)&Bs[nb][rb][cb]     = b0;
      if (kt + 2 < KT) {
        const __bf16* ap = Ap + (size_t)ar * DM + (kt + 2) * 64 + ac;
        a0 = *(const bf16x8*)ap; a1 = *(const bf16x8*)(ap + 8);
        b0 = *(const bf16x8*)(Wp + (size_t)rb * DM + (kt + 2) * 64 + cb);
      }
    }
    __syncthreads();
  }
  const float bv = bias[bn * 64 + nh * 32 + ln];
#pragma unroll
  for (int r = 0; r < 16; ++r) {
    int row = bm * 128 + mq * 32 + (r & 3) + 8 * (r >> 2) + 4 * g;
    out[(size_t)row * DM + bn * 64 + nh * 32 + ln] = acc[r] + bv;
  }
}

// ---------------------------------------------------------------- launch
extern "C" void kernel_launch(void* const* d_in, const int* in_sizes, int n_in,
                              void* d_out, int out_size, void* d_ws, size_t ws_size,
                              hipStream_t stream) {
  const float* Q = (const float*)d_in[0];
  const float* K = (const float*)d_in[1];
  const float* V = (const float*)d_in[2];
  const float* W = (const float*)d_in[3];
  const float* b = (const float*)d_in[4];
  float* out = (float*)d_out;

  __bf16* ws  = (__bf16*)d_ws;
  __bf16* Kb  = ws;
  __bf16* Vtg = Kb + QKV_ELEMS;               // (b,h,d,kv) bf16
  __bf16* Cc  = Vtg + QKV_ELEMS;              // concat (B,S,H,D) bf16
  __bf16* Wt  = Cc + QKV_ELEMS;               // (n,k) bf16

  convert_all<<<dim3(3328, 1, 1), 256, 0, stream>>>(K, V, W, Kb, Vtg, Wt);
  attn<<<dim3(Sn / 64, Hn, Bn), 256, 0, stream>>>(Q, Kb, Vtg, Cc);
  proj<<<dim3(Bn * Sn / 128, DM / 64, 1), 512, 0, stream>>>(Cc, Wt, b, out);
}